// Round 20
// baseline (394.883 us; speedup 1.0000x reference)
//
#include <hip/hip_runtime.h>
#include <hip/hip_bf16.h>

typedef __attribute__((ext_vector_type(4))) float  f32x4;
typedef __attribute__((ext_vector_type(8))) short  bf16x8;
typedef __attribute__((ext_vector_type(4))) float  float4v;
typedef __attribute__((ext_vector_type(8))) unsigned short ushort8;
typedef __attribute__((ext_vector_type(2))) unsigned int uint2v;

#define CIO 128
#define BR  64           // out rows per bucket (one bucket per 64-thread BLOCK)
#define MAXTW 80         // tiles per bucket cap (mean ~40)
#define NB_MAX 4096
#define CSPLIT 8
#define NPASS 6
#define STAGE_CAP 14336

__device__ __forceinline__ unsigned short f2bf(float f) {
  unsigned int u = __float_as_uint(f);
  u = u + 0x7fffu + ((u >> 16) & 1u);
  return (unsigned short)(u >> 16);
}

// Intra-wave LDS fence (rule #18: lgkmcnt + sched_barrier; no s_barrier anywhere)
__device__ __forceinline__ void wave_fence() {
  asm volatile("s_waitcnt lgkmcnt(0)" ::: "memory");
  __builtin_amdgcn_sched_barrier(0);
}

// ============ prep: Wswz[k][kb][nf][lane][8] = B-fragment order ============
__global__ void prep_wswz(const float* __restrict__ W,
                          unsigned short* __restrict__ Wswz, int total) {
  int i = blockIdx.x * 256 + threadIdx.x;
  if (i >= total) return;
  int lane = i & 63;
  int nf   = (i >> 6) & 7;
  int kb   = (i >> 9) & 3;
  int k    = i >> 11;
  int n    = nf * 16 + (lane & 15);
  int c0   = kb * 32 + (lane >> 4) * 8;
  ushort8 v;
  #pragma unroll
  for (int e = 0; e < 8; ++e)
    v[e] = f2bf(W[k * 16384 + (c0 + e) * 128 + n]);
  *(ushort8*)(Wswz + (size_t)i * 8) = v;
}

// ============ prep: fbf = bf16(features) ============
__global__ void prep_fbf(const float* __restrict__ f,
                         unsigned short* __restrict__ fbf, int total8) {
  int i = blockIdx.x * 256 + threadIdx.x;
  if (i >= total8) return;
  const float4v* s = (const float4v*)(f + (size_t)i * 8);
  float4v v0 = s[0], v1 = s[1];
  ushort8 o;
  o[0] = f2bf(v0.x); o[1] = f2bf(v0.y); o[2] = f2bf(v0.z); o[3] = f2bf(v0.w);
  o[4] = f2bf(v1.x); o[5] = f2bf(v1.y); o[6] = f2bf(v1.z); o[7] = f2bf(v1.w);
  *(ushort8*)(fbf + (size_t)i * 8) = o;
}

// ============ build 1: per-(k, M-slice) LDS histogram ============
__global__ __launch_bounds__(1024) void count27p(const int* __restrict__ out_map,
                                                 int* __restrict__ counts,
                                                 int M, int NB, int nkey) {
  __shared__ int h[NB_MAX];
  int k = blockIdx.x, s = blockIdx.y, t = threadIdx.x;
  for (int i = t; i < NB; i += 1024) h[i] = 0;
  __syncthreads();
  int m0 = (int)(((long)s * M) / CSPLIT), m1 = (int)(((long)(s + 1) * M) / CSPLIT);
  for (int m = m0 + t; m < m1; m += 1024)
    atomicAdd(&h[out_map[k * M + m] / BR], 1);
  __syncthreads();
  for (int i = t; i < NB; i += 1024)
    counts[s * nkey + k * NB + i] = h[i];
}

// ============ build 2: hierarchical scan ============
__global__ __launch_bounds__(1024) void scan_p1(const int* __restrict__ counts,
                                                int* __restrict__ offs,
                                                int* __restrict__ bsum, int nkey) {
  __shared__ int part[1024];
  const int t = threadIdx.x;
  const int i = blockIdx.x * 1024 + t;
  int v = 0;
  if (i < nkey) {
    #pragma unroll
    for (int sl = 0; sl < CSPLIT; ++sl) v += counts[sl * nkey + i];
  }
  part[t] = v;
  __syncthreads();
  for (int d = 1; d < 1024; d <<= 1) {
    int x = (t >= d) ? part[t - d] : 0;
    __syncthreads();
    part[t] += x;
    __syncthreads();
  }
  if (i < nkey) offs[i] = part[t] - v;
  if (t == 1023) bsum[blockIdx.x] = part[1023];
}
__global__ void scan_p2(int* __restrict__ bsum, int nb) {
  if (threadIdx.x == 0) {
    int run = 0;
    for (int i = 0; i < nb; ++i) { int c = bsum[i]; bsum[i] = run; run += c; }
    bsum[nb] = run;
  }
}
__global__ __launch_bounds__(1024) void scan_p3(int* __restrict__ offs,
                                                const int* __restrict__ bsum,
                                                int nkey, int nb) {
  const int i = blockIdx.x * 1024 + threadIdx.x;
  if (i < nkey) offs[i] += bsum[blockIdx.x];
  if (i == 0) offs[nkey] = bsum[nb];
}

// ============ build 3: LDS-staged coalesced scatter ============
__global__ __launch_bounds__(1024) void scatter27c(const int* __restrict__ in_map,
                                                   const int* __restrict__ out_map,
                                                   const int* __restrict__ offs,
                                                   unsigned int* __restrict__ sorted,
                                                   int M, int NB) {
  __shared__ unsigned int stage[STAGE_CAP];
  __shared__ int pos[700];
  const int k = blockIdx.x, p = blockIdx.y, t = threadIdx.x;
  const int b0 = (int)(((long)p * NB) / NPASS);
  const int b1 = (int)(((long)(p + 1) * NB) / NPASS);
  const int nb = b1 - b0;
  const int sbase = offs[k * NB + b0];
  const int send  = offs[k * NB + b1];
  const int size  = send - sbase;
  for (int i = t; i < nb; i += 1024) pos[i] = offs[k * NB + b0 + i] - sbase;
  __syncthreads();
  if (size <= STAGE_CAP) {
    for (int m = t; m < M; m += 1024) {
      int o = out_map[k * M + m];
      int bkt = o / BR;
      if (bkt >= b0 && bkt < b1) {
        int q = atomicAdd(&pos[bkt - b0], 1);
        stage[q] = ((unsigned int)in_map[k * M + m] << 7) | (unsigned int)(o & (BR - 1));
      }
    }
    __syncthreads();
    for (int i = t; i < size; i += 1024) sorted[sbase + i] = stage[i];
  } else {
    for (int m = t; m < M; m += 1024) {
      int o = out_map[k * M + m];
      int bkt = o / BR;
      if (bkt >= b0 && bkt < b1) {
        int q = atomicAdd(&pos[bkt - b0], 1);
        sorted[sbase + q] = ((unsigned int)in_map[k * M + m] << 7) | (unsigned int)(o & (BR - 1));
      }
    }
  }
}

// ============ wave helpers ============
__device__ __forceinline__ void load_w(const unsigned int* __restrict__ sorted,
                                       const int* tb, const int* te,
                                       int T, int ntiles, int l16,
                                       unsigned int& w0, unsigned int& w1) {
  w0 = 64u; w1 = 64u;                 // sentinel lrow=64: S annihilates, gather row 0
  if (T < ntiles) {
    int base = tb[T], e = te[T];
    int i0 = base + l16, i1 = base + 16 + l16;
    if (i0 < e) w0 = sorted[i0];
    if (i1 < e) w1 = sorted[i1];
  }
}
__device__ __forceinline__ void load_a(const unsigned short* __restrict__ fbf,
                                       unsigned int w0, unsigned int w1, int lk,
                                       bf16x8* a0, bf16x8* a1) {
  int in0 = (int)(w0 >> 7), in1 = (int)(w1 >> 7);
  #pragma unroll
  for (int kb = 0; kb < 4; ++kb) {
    a0[kb] = *(const bf16x8*)(fbf + (size_t)in0 * CIO + kb * 32 + lk * 8);
    a1[kb] = *(const bf16x8*)(fbf + (size_t)in1 * CIO + kb * 32 + lk * 8);
  }
}
__device__ __forceinline__ void compute_tile_w(const unsigned short* __restrict__ wk,
                                               const bf16x8 a0[4], const bf16x8 a1[4],
                                               unsigned char* sg,
                                               int lane, int l16, int lk, int swz) {
  #pragma unroll
  for (int h = 0; h < 2; ++h) {
    f32x4 acc[2][4] = {};
    __builtin_amdgcn_s_setprio(1);          // T5: favor this wave through its MFMA burst
    #pragma unroll
    for (int kb = 0; kb < 4; ++kb) {
      const unsigned short* wkb = wk + kb * 4096 + h * 2048;
      #pragma unroll
      for (int nf = 0; nf < 4; ++nf) {
        bf16x8 bfr = *(const bf16x8*)(wkb + nf * 512 + lane * 8);
        acc[0][nf] = __builtin_amdgcn_mfma_f32_16x16x32_bf16(a0[kb], bfr, acc[0][nf], 0, 0, 0);
        acc[1][nf] = __builtin_amdgcn_mfma_f32_16x16x32_bf16(a1[kb], bfr, acc[1][nf], 0, 0, 0);
      }
    }
    __builtin_amdgcn_s_setprio(0);
    #pragma unroll
    for (int rg = 0; rg < 2; ++rg)
      #pragma unroll
      for (int nf = 0; nf < 4; ++nf) {
        unsigned int lo = f2bf(acc[rg][nf][0]) | ((unsigned int)f2bf(acc[rg][nf][1]) << 16);
        unsigned int hi = f2bf(acc[rg][nf][2]) | ((unsigned int)f2bf(acc[rg][nf][3]) << 16);
        int c  = h * 64 + nf * 16 + l16;
        int eb = (rg * 16 + lk * 4) * 2;
        *(uint2v*)&sg[c * 128 + (eb ^ swz)] = (uint2v){lo, hi};
      }
  }
}
__device__ __forceinline__ void reduce_w(const unsigned char* __restrict__ lrow,
                                         const unsigned char* __restrict__ sg,
                                         f32x4 racc[4][8],
                                         int l16, int lk, int swz) {
  unsigned long long lr8 = *(const unsigned long long*)&lrow[lk * 8];
  int eb8[8];
  #pragma unroll
  for (int j = 0; j < 8; ++j) eb8[j] = (int)((lr8 >> (8 * j)) & 255ull);
  union { unsigned int u[4]; bf16x8 v; } su[4];
  #pragma unroll
  for (int mt = 0; mt < 4; ++mt) {
    const int target = mt * 16 + l16;
    #pragma unroll
    for (int p = 0; p < 4; ++p)
      su[mt].u[p] = (eb8[2 * p] == target ? 0x3F80u : 0u) |
                    (eb8[2 * p + 1] == target ? 0x3F800000u : 0u);
  }
  const int eoff = (lk * 16) ^ swz;
  __builtin_amdgcn_s_setprio(1);            // T5: favor the reduce MFMA burst
  #pragma unroll
  for (int nf = 0; nf < 8; ++nf) {
    bf16x8 bq = *(const bf16x8*)&sg[(nf * 16 + l16) * 128 + eoff];
    #pragma unroll
    for (int mt = 0; mt < 4; ++mt)
      racc[mt][nf] = __builtin_amdgcn_mfma_f32_16x16x32_bf16(su[mt].v, bq, racc[mt][nf], 0, 0, 0);
  }
  __builtin_amdgcn_s_setprio(0);
}

// ============ WAVE-AUTONOMOUS fused: ONE 64-thread block = one bucket ============
// R17 structure (best: 234us fused) + T5 setprio around MFMA clusters.
// Independent 1-wave blocks at random phases = exactly the regime where
// setprio measured real gains (attn m191); zero correctness risk.
__global__ __launch_bounds__(64) void spconv_wave(
    const unsigned short* __restrict__ fbf,
    const unsigned short* __restrict__ Wswz,
    const unsigned int* __restrict__ sorted,
    const int* __restrict__ offs,
    const float* __restrict__ bias,
    float* __restrict__ out,
    int NB, int n_out, int KVOL) {
  __shared__ __align__(16) unsigned char stag[16384];   // 128ch x 128B (this wave's tile)
  __shared__ __align__(8)  unsigned char lrowb[2][32];
  __shared__ int tb[MAXTW], te[MAXTW];
  __shared__ unsigned char tkk[MAXTW];

  const int lane = threadIdx.x & 63;
  const int l16  = lane & 15;
  const int lk   = lane >> 4;
  const int swz  = (l16 & 7) << 4;
  const int bucket = blockIdx.x;

  // per-wave tile map (lane 0 writes; seg bounds shuffled from lanes 0..KVOL-1)
  int vs = 0, vc = 0;
  if (lane < KVOL) {
    vs = offs[lane * NB + bucket];
    vc = offs[lane * NB + bucket + 1] - vs;
  }
  int ntr = 0;
  for (int k = 0; k < KVOL; ++k) {
    int s = __shfl(vs, k), c = __shfl(vc, k);
    if (lane == 0) {
      for (int t = 0; t < c; t += 32)
        if (ntr < MAXTW) { tkk[ntr] = (unsigned char)k; tb[ntr] = s + t; te[ntr] = s + c; ++ntr; }
    }
  }
  const int nt = __shfl(ntr, 0);
  wave_fence();

  f32x4 racc[4][8];
  #pragma unroll
  for (int mt = 0; mt < 4; ++mt)
    #pragma unroll
    for (int nf = 0; nf < 8; ++nf) racc[mt][nf] = (f32x4){0.f, 0.f, 0.f, 0.f};

  // 2-deep pipeline, named sets (A = even tiles, B = odd tiles)
  unsigned int wA0, wA1, wB0, wB1;
  bf16x8 aA0[4], aA1[4], aB0[4], aB1[4];
  load_w(sorted, tb, te, 0, nt, l16, wA0, wA1);
  if (lk == 0) {
    lrowb[0][l16]      = (unsigned char)(wA0 & 127u);
    lrowb[0][16 + l16] = (unsigned char)(wA1 & 127u);
  }
  load_a(fbf, wA0, wA1, lk, aA0, aA1);
  load_w(sorted, tb, te, 1, nt, l16, wB0, wB1);

  for (int bt = 0; bt < nt; bt += 2) {
    // ---- EVEN: tile bt (set A, lrow slot 0) ----
    wave_fence();                      // prior reduce reads ordered before these writes
    compute_tile_w(Wswz + (size_t)tkk[bt] * 16384, aA0, aA1, stag, lane, l16, lk, swz);
    load_a(fbf, wB0, wB1, lk, aB0, aB1);                 // gathers tile bt+1
    load_w(sorted, tb, te, bt + 2, nt, l16, wA0, wA1);   // words tile bt+2
    if (lk == 0) {
      lrowb[1][l16]      = (unsigned char)(wB0 & 127u);
      lrowb[1][16 + l16] = (unsigned char)(wB1 & 127u);
    }
    wave_fence();                      // stag writes drained before reads
    reduce_w(&lrowb[0][0], stag, racc, l16, lk, swz);

    // ---- ODD: tile bt+1 (set B, lrow slot 1) ----
    wave_fence();
    if (bt + 1 < nt)
      compute_tile_w(Wswz + (size_t)tkk[bt + 1] * 16384, aB0, aB1, stag, lane, l16, lk, swz);
    load_a(fbf, wA0, wA1, lk, aA0, aA1);                 // gathers tile bt+2
    load_w(sorted, tb, te, bt + 3, nt, l16, wB0, wB1);   // words tile bt+3
    if (lk == 0) {
      lrowb[0][l16]      = (unsigned char)(wA0 & 127u);
      lrowb[0][16 + l16] = (unsigned char)(wA1 & 127u);
    }
    wave_fence();
    reduce_w(&lrowb[1][0], stag, racc, l16, lk, swz);    // sentinel-safe if bt+1>=nt
  }

  // epilogue: direct stores — wave owns all 128 ch x 64 rows of its bucket
  {
    float bi[8];
    #pragma unroll
    for (int nf = 0; nf < 8; ++nf) bi[nf] = bias[nf * 16 + l16];
    #pragma unroll
    for (int mt = 0; mt < 4; ++mt)
      #pragma unroll
      for (int r = 0; r < 4; ++r) {
        int orow = bucket * BR + mt * 16 + lk * 4 + r;
        if (orow < n_out) {
          #pragma unroll
          for (int nf = 0; nf < 8; ++nf)
            out[(size_t)orow * CIO + nf * 16 + l16] = racc[mt][nf][r] + bi[nf];
        }
      }
  }
}

// ===================== legacy fallback (tiny ws) =====================
__global__ void prep_weights(const float* __restrict__ W,
                             unsigned short* __restrict__ Wt, int total) {
  int idx = blockIdx.x * 256 + threadIdx.x;
  if (idx >= total) return;
  int k  = idx >> 14;
  int n  = (idx >> 7) & 127;
  int kk = idx & 127;
  Wt[idx] = f2bf(W[k * 16384 + kk * 128 + n]);
}
__global__ void init_bias(float* __restrict__ out,
                          const float* __restrict__ bias, int total4) {
  int idx = blockIdx.x * 256 + threadIdx.x;
  if (idx >= total4) return;
  float4v b = ((const float4v*)bias)[idx & 31];
  ((float4v*)out)[idx] = b;
}
__global__ __launch_bounds__(256) void spconv_mfma_legacy(
    const float* __restrict__ features, const unsigned short* __restrict__ Wt,
    const int* __restrict__ in_map, const int* __restrict__ out_map,
    float* __restrict__ out, int M) {
  const int ky = blockIdx.y, m0 = blockIdx.x * 64, tid = threadIdx.x;
  __shared__ unsigned short Alds[64 * CIO];
  __shared__ unsigned short Blds[CIO * CIO];
  {
    const ushort8* src = (const ushort8*)(Wt + ky * 16384);
    #pragma unroll
    for (int i = 0; i < 8; ++i) {
      int chunk = tid + i * 256, byte = chunk * 16;
      int row = byte >> 8, off = byte & 255, sw = off ^ ((row & 7) << 4);
      *(ushort8*)((char*)Blds + row * 256 + sw) = src[chunk];
    }
  }
  {
    int r = tid >> 2, q = tid & 3, m = m0 + r;
    unsigned short tmp[32];
    if (m < M) {
      int frow = in_map[ky * M + m];
      const float4v* src = (const float4v*)(features + frow * CIO + q * 32);
      #pragma unroll
      for (int i = 0; i < 8; ++i) {
        float4v v = src[i];
        tmp[i*4+0]=f2bf(v.x); tmp[i*4+1]=f2bf(v.y); tmp[i*4+2]=f2bf(v.z); tmp[i*4+3]=f2bf(v.w);
      }
    } else {
      #pragma unroll
      for (int i = 0; i < 32; ++i) tmp[i] = 0;
    }
    #pragma unroll
    for (int c = 0; c < 4; ++c) {
      int off = q * 64 + c * 16, sw = off ^ ((r & 7) << 4);
      *(ushort8*)((char*)Alds + r * 256 + sw) = *(ushort8*)(tmp + c * 8);
    }
  }
  __syncthreads();
  const int wid = tid >> 6, lane = tid & 63;
  const int wm = wid >> 1, wn = wid & 1, l16 = lane & 15, lk = lane >> 4;
  f32x4 acc[2][4] = {};
  #pragma unroll
  for (int kb = 0; kb < CIO; kb += 32) {
    bf16x8 af[2], bfr[4];
    #pragma unroll
    for (int mf = 0; mf < 2; ++mf) {
      int row = wm * 32 + mf * 16 + l16, off = (kb + lk * 8) * 2;
      int sw = off ^ ((row & 7) << 4);
      af[mf] = *(const bf16x8*)((const char*)Alds + row * 256 + sw);
    }
    #pragma unroll
    for (int nf = 0; nf < 4; ++nf) {
      int n = wn * 64 + nf * 16 + l16, off = (kb + lk * 8) * 2;
      int sw = off ^ ((n & 7) << 4);
      bfr[nf] = *(const bf16x8*)((const char*)Blds + n * 256 + sw);
    }
    #pragma unroll
    for (int mf = 0; mf < 2; ++mf)
      #pragma unroll
      for (int nf = 0; nf < 4; ++nf)
        acc[mf][nf] = __builtin_amdgcn_mfma_f32_16x16x32_bf16(af[mf], bfr[nf], acc[mf][nf], 0, 0, 0);
  }
  #pragma unroll
  for (int mf = 0; mf < 2; ++mf)
    #pragma unroll
    for (int r = 0; r < 4; ++r) {
      int mrow = wm * 32 + mf * 16 + lk * 4 + r, m = m0 + mrow;
      if (m < M) {
        int orow = out_map[ky * M + m];
        float* dst = out + orow * CIO + wn * 64 + l16;
        #pragma unroll
        for (int nf = 0; nf < 4; ++nf) unsafeAtomicAdd(dst + nf * 16, acc[mf][nf][r]);
      }
    }
}

static inline size_t align256(size_t x) { return (x + 255) & ~(size_t)255; }

extern "C" void kernel_launch(void* const* d_in, const int* in_sizes, int n_in,
                              void* d_out, int out_size, void* d_ws, size_t ws_size,
                              hipStream_t stream) {
  const float* features = (const float*)d_in[0];
  const float* W        = (const float*)d_in[1];
  const float* bias     = (const float*)d_in[2];
  const int*   in_map   = (const int*)d_in[3];
  const int*   out_map  = (const int*)d_in[4];
  float*       out      = (float*)d_out;

  const int KVOL  = in_sizes[1] / (CIO * CIO);     // 27
  const int M     = in_sizes[3] / KVOL;            // 50000
  const int n_out = out_size / CIO;                // 100000
  const int N_IN  = in_sizes[0] / CIO;             // 100000
  const int NB    = (n_out + BR - 1) / BR;         // 1563
  const int NKEY  = KVOL * NB;
  const size_t KM = (size_t)KVOL * M;

  const size_t s_wswz = (size_t)KVOL * CIO * CIO * 2;
  const size_t o_cnt  = align256(s_wswz);
  const size_t o_offs = align256(o_cnt + (size_t)CSPLIT * NKEY * 4);
  const size_t o_bsum = align256(o_offs + ((size_t)NKEY + 1) * 4);
  const size_t o_sort = align256(o_bsum + 4096 * 4);
  const size_t o_fbf  = align256(o_sort + KM * 4);
  const size_t need   = o_fbf + (size_t)N_IN * CIO * 2;

  if (NB <= NB_MAX && KVOL <= 32 && ws_size >= need) {
    unsigned short* Wswz   = (unsigned short*)d_ws;
    int*            cnt    = (int*)((char*)d_ws + o_cnt);
    int*            offs   = (int*)((char*)d_ws + o_offs);
    int*            bsum   = (int*)((char*)d_ws + o_bsum);
    unsigned int*   sorted = (unsigned int*)((char*)d_ws + o_sort);
    unsigned short* fbf    = (unsigned short*)((char*)d_ws + o_fbf);

    int wtot = KVOL * 4 * 8 * 64;
    prep_wswz<<<(wtot + 255) / 256, 256, 0, stream>>>(W, Wswz, wtot);
    int total8 = N_IN * CIO / 8;
    prep_fbf<<<(total8 + 255) / 256, 256, 0, stream>>>(features, fbf, total8);
    count27p<<<dim3(KVOL, CSPLIT), 1024, 0, stream>>>(out_map, cnt, M, NB, NKEY);

    const int nsb = (NKEY + 1023) / 1024;
    scan_p1<<<nsb, 1024, 0, stream>>>(cnt, offs, bsum, NKEY);
    scan_p2<<<1, 64, 0, stream>>>(bsum, nsb);
    scan_p3<<<nsb, 1024, 0, stream>>>(offs, bsum, NKEY, nsb);

    scatter27c<<<dim3(KVOL, NPASS), 1024, 0, stream>>>(in_map, out_map, offs, sorted, M, NB);

    spconv_wave<<<NB, 64, 0, stream>>>(fbf, Wswz, sorted, offs, bias, out,
                                       NB, n_out, KVOL);
  } else {
    unsigned short* Wt = (unsigned short*)d_ws;
    if (ws_size < s_wswz) return;
    int wtot = KVOL * CIO * CIO;
    prep_weights<<<(wtot + 255) / 256, 256, 0, stream>>>(W, Wt, wtot);
    int total4 = out_size / 4;
    init_bias<<<(total4 + 255) / 256, 256, 0, stream>>>(out, bias, total4);
    dim3 grid((M + 63) / 64, KVOL);
    spconv_mfma_legacy<<<grid, 256, 0, stream>>>(features, Wt, in_map, out_map, out, M);
  }
}

// Round 21
// 285.399 us; speedup vs baseline: 1.3836x; 1.3836x over previous
//
#include <hip/hip_runtime.h>
#include <hip/hip_bf16.h>

typedef __attribute__((ext_vector_type(4))) float  f32x4;
typedef __attribute__((ext_vector_type(8))) short  bf16x8;
typedef __attribute__((ext_vector_type(4))) float  float4v;
typedef __attribute__((ext_vector_type(8))) unsigned short ushort8;
typedef __attribute__((ext_vector_type(2))) unsigned int uint2v;

#define CIO 128
#define BR  64           // out rows per bucket (one bucket per 64-thread BLOCK)
#define MAXTW 80         // tiles per bucket cap (mean ~40)
#define NB_MAX 4096
#define CSPLIT 8
#define NPASS 6
#define STAGE_CAP 14336

__device__ __forceinline__ unsigned short f2bf(float f) {
  unsigned int u = __float_as_uint(f);
  u = u + 0x7fffu + ((u >> 16) & 1u);
  return (unsigned short)(u >> 16);
}

// Intra-wave LDS fence (rule #18: lgkmcnt + sched_barrier; no s_barrier anywhere)
__device__ __forceinline__ void wave_fence() {
  asm volatile("s_waitcnt lgkmcnt(0)" ::: "memory");
  __builtin_amdgcn_sched_barrier(0);
}

// ============ prep: Wswz[k][kb][nf][lane][8] = B-fragment order ============
__global__ void prep_wswz(const float* __restrict__ W,
                          unsigned short* __restrict__ Wswz, int total) {
  int i = blockIdx.x * 256 + threadIdx.x;
  if (i >= total) return;
  int lane = i & 63;
  int nf   = (i >> 6) & 7;
  int kb   = (i >> 9) & 3;
  int k    = i >> 11;
  int n    = nf * 16 + (lane & 15);
  int c0   = kb * 32 + (lane >> 4) * 8;
  ushort8 v;
  #pragma unroll
  for (int e = 0; e < 8; ++e)
    v[e] = f2bf(W[k * 16384 + (c0 + e) * 128 + n]);
  *(ushort8*)(Wswz + (size_t)i * 8) = v;
}

// ============ prep: fbf = bf16(features) ============
__global__ void prep_fbf(const float* __restrict__ f,
                         unsigned short* __restrict__ fbf, int total8) {
  int i = blockIdx.x * 256 + threadIdx.x;
  if (i >= total8) return;
  const float4v* s = (const float4v*)(f + (size_t)i * 8);
  float4v v0 = s[0], v1 = s[1];
  ushort8 o;
  o[0] = f2bf(v0.x); o[1] = f2bf(v0.y); o[2] = f2bf(v0.z); o[3] = f2bf(v0.w);
  o[4] = f2bf(v1.x); o[5] = f2bf(v1.y); o[6] = f2bf(v1.z); o[7] = f2bf(v1.w);
  *(ushort8*)(fbf + (size_t)i * 8) = o;
}

// ============ build 1: per-(k, M-slice) LDS histogram ============
__global__ __launch_bounds__(1024) void count27p(const int* __restrict__ out_map,
                                                 int* __restrict__ counts,
                                                 int M, int NB, int nkey) {
  __shared__ int h[NB_MAX];
  int k = blockIdx.x, s = blockIdx.y, t = threadIdx.x;
  for (int i = t; i < NB; i += 1024) h[i] = 0;
  __syncthreads();
  int m0 = (int)(((long)s * M) / CSPLIT), m1 = (int)(((long)(s + 1) * M) / CSPLIT);
  for (int m = m0 + t; m < m1; m += 1024)
    atomicAdd(&h[out_map[k * M + m] / BR], 1);
  __syncthreads();
  for (int i = t; i < NB; i += 1024)
    counts[s * nkey + k * NB + i] = h[i];
}

// ============ build 2: hierarchical scan ============
__global__ __launch_bounds__(1024) void scan_p1(const int* __restrict__ counts,
                                                int* __restrict__ offs,
                                                int* __restrict__ bsum, int nkey) {
  __shared__ int part[1024];
  const int t = threadIdx.x;
  const int i = blockIdx.x * 1024 + t;
  int v = 0;
  if (i < nkey) {
    #pragma unroll
    for (int sl = 0; sl < CSPLIT; ++sl) v += counts[sl * nkey + i];
  }
  part[t] = v;
  __syncthreads();
  for (int d = 1; d < 1024; d <<= 1) {
    int x = (t >= d) ? part[t - d] : 0;
    __syncthreads();
    part[t] += x;
    __syncthreads();
  }
  if (i < nkey) offs[i] = part[t] - v;
  if (t == 1023) bsum[blockIdx.x] = part[1023];
}
__global__ void scan_p2(int* __restrict__ bsum, int nb) {
  if (threadIdx.x == 0) {
    int run = 0;
    for (int i = 0; i < nb; ++i) { int c = bsum[i]; bsum[i] = run; run += c; }
    bsum[nb] = run;
  }
}
__global__ __launch_bounds__(1024) void scan_p3(int* __restrict__ offs,
                                                const int* __restrict__ bsum,
                                                int nkey, int nb) {
  const int i = blockIdx.x * 1024 + threadIdx.x;
  if (i < nkey) offs[i] += bsum[blockIdx.x];
  if (i == 0) offs[nkey] = bsum[nb];
}

// ============ build 3: LDS-staged coalesced scatter ============
__global__ __launch_bounds__(1024) void scatter27c(const int* __restrict__ in_map,
                                                   const int* __restrict__ out_map,
                                                   const int* __restrict__ offs,
                                                   unsigned int* __restrict__ sorted,
                                                   int M, int NB) {
  __shared__ unsigned int stage[STAGE_CAP];
  __shared__ int pos[700];
  const int k = blockIdx.x, p = blockIdx.y, t = threadIdx.x;
  const int b0 = (int)(((long)p * NB) / NPASS);
  const int b1 = (int)(((long)(p + 1) * NB) / NPASS);
  const int nb = b1 - b0;
  const int sbase = offs[k * NB + b0];
  const int send  = offs[k * NB + b1];
  const int size  = send - sbase;
  for (int i = t; i < nb; i += 1024) pos[i] = offs[k * NB + b0 + i] - sbase;
  __syncthreads();
  if (size <= STAGE_CAP) {
    for (int m = t; m < M; m += 1024) {
      int o = out_map[k * M + m];
      int bkt = o / BR;
      if (bkt >= b0 && bkt < b1) {
        int q = atomicAdd(&pos[bkt - b0], 1);
        stage[q] = ((unsigned int)in_map[k * M + m] << 7) | (unsigned int)(o & (BR - 1));
      }
    }
    __syncthreads();
    for (int i = t; i < size; i += 1024) sorted[sbase + i] = stage[i];
  } else {
    for (int m = t; m < M; m += 1024) {
      int o = out_map[k * M + m];
      int bkt = o / BR;
      if (bkt >= b0 && bkt < b1) {
        int q = atomicAdd(&pos[bkt - b0], 1);
        sorted[sbase + q] = ((unsigned int)in_map[k * M + m] << 7) | (unsigned int)(o & (BR - 1));
      }
    }
  }
}

// ============ wave helpers ============
__device__ __forceinline__ void load_w(const unsigned int* __restrict__ sorted,
                                       const int* tb, const int* te,
                                       int T, int ntiles, int l16,
                                       unsigned int& w0, unsigned int& w1) {
  w0 = 64u; w1 = 64u;                 // sentinel lrow=64: S annihilates, gather row 0
  if (T < ntiles) {
    int base = tb[T], e = te[T];
    int i0 = base + l16, i1 = base + 16 + l16;
    if (i0 < e) w0 = sorted[i0];
    if (i1 < e) w1 = sorted[i1];
  }
}
__device__ __forceinline__ void load_a(const unsigned short* __restrict__ fbf,
                                       unsigned int w0, unsigned int w1, int lk,
                                       bf16x8* a0, bf16x8* a1) {
  int in0 = (int)(w0 >> 7), in1 = (int)(w1 >> 7);
  #pragma unroll
  for (int kb = 0; kb < 4; ++kb) {
    a0[kb] = *(const bf16x8*)(fbf + (size_t)in0 * CIO + kb * 32 + lk * 8);
    a1[kb] = *(const bf16x8*)(fbf + (size_t)in1 * CIO + kb * 32 + lk * 8);
  }
}
// Compute one 32-entry tile into the wave's PRIVATE stag slice [128ch][128B].
__device__ __forceinline__ void compute_tile_w(const unsigned short* __restrict__ wk,
                                               const bf16x8 a0[4], const bf16x8 a1[4],
                                               unsigned char* sg,
                                               int lane, int l16, int lk, int swz) {
  #pragma unroll
  for (int h = 0; h < 2; ++h) {
    f32x4 acc[2][4] = {};
    #pragma unroll
    for (int kb = 0; kb < 4; ++kb) {
      const unsigned short* wkb = wk + kb * 4096 + h * 2048;
      #pragma unroll
      for (int nf = 0; nf < 4; ++nf) {
        bf16x8 bfr = *(const bf16x8*)(wkb + nf * 512 + lane * 8);
        acc[0][nf] = __builtin_amdgcn_mfma_f32_16x16x32_bf16(a0[kb], bfr, acc[0][nf], 0, 0, 0);
        acc[1][nf] = __builtin_amdgcn_mfma_f32_16x16x32_bf16(a1[kb], bfr, acc[1][nf], 0, 0, 0);
      }
    }
    #pragma unroll
    for (int rg = 0; rg < 2; ++rg)
      #pragma unroll
      for (int nf = 0; nf < 4; ++nf) {
        unsigned int lo = f2bf(acc[rg][nf][0]) | ((unsigned int)f2bf(acc[rg][nf][1]) << 16);
        unsigned int hi = f2bf(acc[rg][nf][2]) | ((unsigned int)f2bf(acc[rg][nf][3]) << 16);
        int c  = h * 64 + nf * 16 + l16;
        int eb = (rg * 16 + lk * 4) * 2;
        *(uint2v*)&sg[c * 128 + (eb ^ swz)] = (uint2v){lo, hi};
      }
  }
}
__device__ __forceinline__ void reduce_w(const unsigned char* __restrict__ lrow,
                                         const unsigned char* __restrict__ sg,
                                         f32x4 racc[4][8],
                                         int l16, int lk, int swz) {
  unsigned long long lr8 = *(const unsigned long long*)&lrow[lk * 8];
  int eb8[8];
  #pragma unroll
  for (int j = 0; j < 8; ++j) eb8[j] = (int)((lr8 >> (8 * j)) & 255ull);
  union { unsigned int u[4]; bf16x8 v; } su[4];
  #pragma unroll
  for (int mt = 0; mt < 4; ++mt) {
    const int target = mt * 16 + l16;
    #pragma unroll
    for (int p = 0; p < 4; ++p)
      su[mt].u[p] = (eb8[2 * p] == target ? 0x3F80u : 0u) |
                    (eb8[2 * p + 1] == target ? 0x3F800000u : 0u);
  }
  const int eoff = (lk * 16) ^ swz;
  #pragma unroll
  for (int nf = 0; nf < 8; ++nf) {
    bf16x8 bq = *(const bf16x8*)&sg[(nf * 16 + l16) * 128 + eoff];
    #pragma unroll
    for (int mt = 0; mt < 4; ++mt)
      racc[mt][nf] = __builtin_amdgcn_mfma_f32_16x16x32_bf16(su[mt].v, bq, racc[mt][nf], 0, 0, 0);
  }
}

// ============ WAVE-AUTONOMOUS fused: ONE 64-thread block = one bucket ============
// Session-best structure (R17: fused 234us, total 286us). Zero s_barrier;
// per-wave private stag; 2-deep named-set pipeline; S-matmul reduce.
// R18 (channel-split occupancy), R19 (fence-free rotation), R20 (setprio)
// all regressed against this baseline — locked in as final.
__global__ __launch_bounds__(64) void spconv_wave(
    const unsigned short* __restrict__ fbf,
    const unsigned short* __restrict__ Wswz,
    const unsigned int* __restrict__ sorted,
    const int* __restrict__ offs,
    const float* __restrict__ bias,
    float* __restrict__ out,
    int NB, int n_out, int KVOL) {
  __shared__ __align__(16) unsigned char stag[16384];   // 128ch x 128B (this wave's tile)
  __shared__ __align__(8)  unsigned char lrowb[2][32];
  __shared__ int tb[MAXTW], te[MAXTW];
  __shared__ unsigned char tkk[MAXTW];

  const int lane = threadIdx.x & 63;
  const int l16  = lane & 15;
  const int lk   = lane >> 4;
  const int swz  = (l16 & 7) << 4;
  const int bucket = blockIdx.x;

  // per-wave tile map (lane 0 writes; seg bounds shuffled from lanes 0..KVOL-1)
  int vs = 0, vc = 0;
  if (lane < KVOL) {
    vs = offs[lane * NB + bucket];
    vc = offs[lane * NB + bucket + 1] - vs;
  }
  int ntr = 0;
  for (int k = 0; k < KVOL; ++k) {
    int s = __shfl(vs, k), c = __shfl(vc, k);
    if (lane == 0) {
      for (int t = 0; t < c; t += 32)
        if (ntr < MAXTW) { tkk[ntr] = (unsigned char)k; tb[ntr] = s + t; te[ntr] = s + c; ++ntr; }
    }
  }
  const int nt = __shfl(ntr, 0);
  wave_fence();

  f32x4 racc[4][8];
  #pragma unroll
  for (int mt = 0; mt < 4; ++mt)
    #pragma unroll
    for (int nf = 0; nf < 8; ++nf) racc[mt][nf] = (f32x4){0.f, 0.f, 0.f, 0.f};

  // 2-deep pipeline, named sets (A = even tiles, B = odd tiles)
  unsigned int wA0, wA1, wB0, wB1;
  bf16x8 aA0[4], aA1[4], aB0[4], aB1[4];
  load_w(sorted, tb, te, 0, nt, l16, wA0, wA1);
  if (lk == 0) {
    lrowb[0][l16]      = (unsigned char)(wA0 & 127u);
    lrowb[0][16 + l16] = (unsigned char)(wA1 & 127u);
  }
  load_a(fbf, wA0, wA1, lk, aA0, aA1);
  load_w(sorted, tb, te, 1, nt, l16, wB0, wB1);

  for (int bt = 0; bt < nt; bt += 2) {
    // ---- EVEN: tile bt (set A, lrow slot 0) ----
    wave_fence();                      // prior reduce reads ordered before these writes
    compute_tile_w(Wswz + (size_t)tkk[bt] * 16384, aA0, aA1, stag, lane, l16, lk, swz);
    load_a(fbf, wB0, wB1, lk, aB0, aB1);                 // gathers tile bt+1
    load_w(sorted, tb, te, bt + 2, nt, l16, wA0, wA1);   // words tile bt+2
    if (lk == 0) {
      lrowb[1][l16]      = (unsigned char)(wB0 & 127u);
      lrowb[1][16 + l16] = (unsigned char)(wB1 & 127u);
    }
    wave_fence();                      // stag writes drained before reads
    reduce_w(&lrowb[0][0], stag, racc, l16, lk, swz);

    // ---- ODD: tile bt+1 (set B, lrow slot 1) ----
    wave_fence();
    if (bt + 1 < nt)
      compute_tile_w(Wswz + (size_t)tkk[bt + 1] * 16384, aB0, aB1, stag, lane, l16, lk, swz);
    load_a(fbf, wA0, wA1, lk, aA0, aA1);                 // gathers tile bt+2
    load_w(sorted, tb, te, bt + 3, nt, l16, wB0, wB1);   // words tile bt+3
    if (lk == 0) {
      lrowb[0][l16]      = (unsigned char)(wA0 & 127u);
      lrowb[0][16 + l16] = (unsigned char)(wA1 & 127u);
    }
    wave_fence();
    reduce_w(&lrowb[1][0], stag, racc, l16, lk, swz);    // sentinel-safe if bt+1>=nt
  }

  // epilogue: direct stores — wave owns all 128 ch x 64 rows of its bucket
  {
    float bi[8];
    #pragma unroll
    for (int nf = 0; nf < 8; ++nf) bi[nf] = bias[nf * 16 + l16];
    #pragma unroll
    for (int mt = 0; mt < 4; ++mt)
      #pragma unroll
      for (int r = 0; r < 4; ++r) {
        int orow = bucket * BR + mt * 16 + lk * 4 + r;
        if (orow < n_out) {
          #pragma unroll
          for (int nf = 0; nf < 8; ++nf)
            out[(size_t)orow * CIO + nf * 16 + l16] = racc[mt][nf][r] + bi[nf];
        }
      }
  }
}

// ===================== legacy fallback (tiny ws) =====================
__global__ void prep_weights(const float* __restrict__ W,
                             unsigned short* __restrict__ Wt, int total) {
  int idx = blockIdx.x * 256 + threadIdx.x;
  if (idx >= total) return;
  int k  = idx >> 14;
  int n  = (idx >> 7) & 127;
  int kk = idx & 127;
  Wt[idx] = f2bf(W[k * 16384 + kk * 128 + n]);
}
__global__ void init_bias(float* __restrict__ out,
                          const float* __restrict__ bias, int total4) {
  int idx = blockIdx.x * 256 + threadIdx.x;
  if (idx >= total4) return;
  float4v b = ((const float4v*)bias)[idx & 31];
  ((float4v*)out)[idx] = b;
}
__global__ __launch_bounds__(256) void spconv_mfma_legacy(
    const float* __restrict__ features, const unsigned short* __restrict__ Wt,
    const int* __restrict__ in_map, const int* __restrict__ out_map,
    float* __restrict__ out, int M) {
  const int ky = blockIdx.y, m0 = blockIdx.x * 64, tid = threadIdx.x;
  __shared__ unsigned short Alds[64 * CIO];
  __shared__ unsigned short Blds[CIO * CIO];
  {
    const ushort8* src = (const ushort8*)(Wt + ky * 16384);
    #pragma unroll
    for (int i = 0; i < 8; ++i) {
      int chunk = tid + i * 256, byte = chunk * 16;
      int row = byte >> 8, off = byte & 255, sw = off ^ ((row & 7) << 4);
      *(ushort8*)((char*)Blds + row * 256 + sw) = src[chunk];
    }
  }
  {
    int r = tid >> 2, q = tid & 3, m = m0 + r;
    unsigned short tmp[32];
    if (m < M) {
      int frow = in_map[ky * M + m];
      const float4v* src = (const float4v*)(features + frow * CIO + q * 32);
      #pragma unroll
      for (int i = 0; i < 8; ++i) {
        float4v v = src[i];
        tmp[i*4+0]=f2bf(v.x); tmp[i*4+1]=f2bf(v.y); tmp[i*4+2]=f2bf(v.z); tmp[i*4+3]=f2bf(v.w);
      }
    } else {
      #pragma unroll
      for (int i = 0; i < 32; ++i) tmp[i] = 0;
    }
    #pragma unroll
    for (int c = 0; c < 4; ++c) {
      int off = q * 64 + c * 16, sw = off ^ ((r & 7) << 4);
      *(ushort8*)((char*)Alds + r * 256 + sw) = *(ushort8*)(tmp + c * 8);
    }
  }
  __syncthreads();
  const int wid = tid >> 6, lane = tid & 63;
  const int wm = wid >> 1, wn = wid & 1, l16 = lane & 15, lk = lane >> 4;
  f32x4 acc[2][4] = {};
  #pragma unroll
  for (int kb = 0; kb < CIO; kb += 32) {
    bf16x8 af[2], bfr[4];
    #pragma unroll
    for (int mf = 0; mf < 2; ++mf) {
      int row = wm * 32 + mf * 16 + l16, off = (kb + lk * 8) * 2;
      int sw = off ^ ((row & 7) << 4);
      af[mf] = *(const bf16x8*)((const char*)Alds + row * 256 + sw);
    }
    #pragma unroll
    for (int nf = 0; nf < 4; ++nf) {
      int n = wn * 64 + nf * 16 + l16, off = (kb + lk * 8) * 2;
      int sw = off ^ ((n & 7) << 4);
      bfr[nf] = *(const bf16x8*)((const char*)Blds + n * 256 + sw);
    }
    #pragma unroll
    for (int mf = 0; mf < 2; ++mf)
      #pragma unroll
      for (int nf = 0; nf < 4; ++nf)
        acc[mf][nf] = __builtin_amdgcn_mfma_f32_16x16x32_bf16(af[mf], bfr[nf], acc[mf][nf], 0, 0, 0);
  }
  #pragma unroll
  for (int mf = 0; mf < 2; ++mf)
    #pragma unroll
    for (int r = 0; r < 4; ++r) {
      int mrow = wm * 32 + mf * 16 + lk * 4 + r, m = m0 + mrow;
      if (m < M) {
        int orow = out_map[ky * M + m];
        float* dst = out + orow * CIO + wn * 64 + l16;
        #pragma unroll
        for (int nf = 0; nf < 4; ++nf) unsafeAtomicAdd(dst + nf * 16, acc[mf][nf][r]);
      }
    }
}

static inline size_t align256(size_t x) { return (x + 255) & ~(size_t)255; }

extern "C" void kernel_launch(void* const* d_in, const int* in_sizes, int n_in,
                              void* d_out, int out_size, void* d_ws, size_t ws_size,
                              hipStream_t stream) {
  const float* features = (const float*)d_in[0];
  const float* W        = (const float*)d_in[1];
  const float* bias     = (const float*)d_in[2];
  const int*   in_map   = (const int*)d_in[3];
  const int*   out_map  = (const int*)d_in[4];
  float*       out      = (float*)d_out;

  const int KVOL  = in_sizes[1] / (CIO * CIO);     // 27
  const int M     = in_sizes[3] / KVOL;            // 50000
  const int n_out = out_size / CIO;                // 100000
  const int N_IN  = in_sizes[0] / CIO;             // 100000
  const int NB    = (n_out + BR - 1) / BR;         // 1563
  const int NKEY  = KVOL * NB;
  const size_t KM = (size_t)KVOL * M;

  const size_t s_wswz = (size_t)KVOL * CIO * CIO * 2;
  const size_t o_cnt  = align256(s_wswz);
  const size_t o_offs = align256(o_cnt + (size_t)CSPLIT * NKEY * 4);
  const size_t o_bsum = align256(o_offs + ((size_t)NKEY + 1) * 4);
  const size_t o_sort = align256(o_bsum + 4096 * 4);
  const size_t o_fbf  = align256(o_sort + KM * 4);
  const size_t need   = o_fbf + (size_t)N_IN * CIO * 2;

  if (NB <= NB_MAX && KVOL <= 32 && ws_size >= need) {
    unsigned short* Wswz   = (unsigned short*)d_ws;
    int*            cnt    = (int*)((char*)d_ws + o_cnt);
    int*            offs   = (int*)((char*)d_ws + o_offs);
    int*            bsum   = (int*)((char*)d_ws + o_bsum);
    unsigned int*   sorted = (unsigned int*)((char*)d_ws + o_sort);
    unsigned short* fbf    = (unsigned short*)((char*)d_ws + o_fbf);

    int wtot = KVOL * 4 * 8 * 64;
    prep_wswz<<<(wtot + 255) / 256, 256, 0, stream>>>(W, Wswz, wtot);
    int total8 = N_IN * CIO / 8;
    prep_fbf<<<(total8 + 255) / 256, 256, 0, stream>>>(features, fbf, total8);
    count27p<<<dim3(KVOL, CSPLIT), 1024, 0, stream>>>(out_map, cnt, M, NB, NKEY);

    const int nsb = (NKEY + 1023) / 1024;
    scan_p1<<<nsb, 1024, 0, stream>>>(cnt, offs, bsum, NKEY);
    scan_p2<<<1, 64, 0, stream>>>(bsum, nsb);
    scan_p3<<<nsb, 1024, 0, stream>>>(offs, bsum, NKEY, nsb);

    scatter27c<<<dim3(KVOL, NPASS), 1024, 0, stream>>>(in_map, out_map, offs, sorted, M, NB);

    spconv_wave<<<NB, 64, 0, stream>>>(fbf, Wswz, sorted, offs, bias, out,
                                       NB, n_out, KVOL);
  } else {
    unsigned short* Wt = (unsigned short*)d_ws;
    if (ws_size < s_wswz) return;
    int wtot = KVOL * CIO * CIO;
    prep_weights<<<(wtot + 255) / 256, 256, 0, stream>>>(W, Wt, wtot);
    int total4 = out_size / 4;
    init_bias<<<(total4 + 255) / 256, 256, 0, stream>>>(out, bias, total4);
    dim3 grid((M + 63) / 64, KVOL);
    spconv_mfma_legacy<<<grid, 256, 0, stream>>>(features, Wt, in_map, out_map, out, M);
  }
}